// Round 4
// baseline (557.458 us; speedup 1.0000x reference)
//
#include <hip/hip_runtime.h>

typedef unsigned short u16;
typedef __bf16 bf16x8 __attribute__((ext_vector_type(8)));
typedef short s16x4 __attribute__((ext_vector_type(4)));
typedef float f32x4 __attribute__((ext_vector_type(4)));

#define S_LEN 2048
#define NHEAD 16
#define QHEAD 192
#define EPS 1e-6f
#define ATTN_SCALE 0.07216878364870323f   /* 192^-0.5 */
#define QSCALE_LOG2E 0.10412011228586118f /* ATTN_SCALE * log2(e) */

__device__ __forceinline__ u16 f2bf(float f) {
    unsigned u = __builtin_bit_cast(unsigned, f);
    u = (u + 0x7FFFu + ((u >> 16) & 1u)) >> 16;
    return (u16)u;
}
__device__ __forceinline__ float bf2f(u16 h) {
    unsigned u = ((unsigned)h) << 16;
    return __builtin_bit_cast(float, u);
}

__device__ __forceinline__ void gl_lds16(const u16* g, u16* l) {
    __builtin_amdgcn_global_load_lds(
        (const __attribute__((address_space(1))) unsigned int*)g,
        (__attribute__((address_space(3))) unsigned int*)l,
        16, 0, 0);
}

#if defined(__has_builtin) && __has_builtin(__builtin_amdgcn_mfma_f32_16x16x16bf16_1k)
__device__ __forceinline__ f32x4 mfma16(s16x4 a, s16x4 b, f32x4 c) {
    return __builtin_amdgcn_mfma_f32_16x16x16bf16_1k(a, b, c, 0, 0, 0);
}
#else
__device__ __forceinline__ f32x4 mfma16(s16x4 a, s16x4 b, f32x4 c) {
    asm volatile("v_mfma_f32_16x16x16_bf16 %0, %1, %2, %0"
                 : "+v"(c) : "v"(a), "v"(b));
    return c;
}
#endif

// ---------------------------------------------------------------------------
// bf16 GEMM:  C[M][N] = A[M][K] @ Bt[N][K]^T   (m97-structure, conflict-free)
// ---------------------------------------------------------------------------
template <int CF32>
__global__ __launch_bounds__(256, 2)
void gemm_bt(const u16* __restrict__ A, const u16* __restrict__ B,
             void* __restrict__ Cv, int K, int lda, int ldb, int ldc)
{
    const int tid = threadIdx.x;
    const int wave = tid >> 6, lane = tid & 63;
    const int q = lane >> 4, r = lane & 15;
    const int tm = blockIdx.y, tn = blockIdx.x;

    __shared__ __align__(16) u16 Al[128 * 32];
    __shared__ __align__(16) u16 Bl[128 * 32];

    const int lr = lane & 15;
    const int lc = (lane >> 4) * 8;
    const u16* ag0 = A + (long)(tm * 128 + wave * 32 + lr) * lda + lc;
    const u16* ag1 = ag0 + 16 * (long)lda;
    const u16* bg0 = B + (long)(tn * 128 + wave * 32 + lr) * ldb + lc;
    const u16* bg1 = bg0 + 16 * (long)ldb;
    u16* al0 = &Al[wave * 1024];
    u16* al1 = &Al[wave * 1024 + 512];
    u16* bl0 = &Bl[wave * 1024];
    u16* bl1 = &Bl[wave * 1024 + 512];

    f32x4 acc[4][4] = {};
    const int cm = (wave >> 1) * 4;
    const int cn = (wave & 1) * 4;

    for (int k0 = 0; k0 < K; k0 += 32) {
        gl_lds16(ag0 + k0, al0);
        gl_lds16(ag1 + k0, al1);
        gl_lds16(bg0 + k0, bl0);
        gl_lds16(bg1 + k0, bl1);
        __syncthreads();
        bf16x8 af[4], bv[4];
        #pragma unroll
        for (int mt = 0; mt < 4; ++mt) af[mt] = *(const bf16x8*)&Al[(cm + mt) * 512 + lane * 8];
        #pragma unroll
        for (int nt = 0; nt < 4; ++nt) bv[nt] = *(const bf16x8*)&Bl[(cn + nt) * 512 + lane * 8];
        #pragma unroll
        for (int mt = 0; mt < 4; ++mt)
            #pragma unroll
            for (int nt = 0; nt < 4; ++nt)
                acc[mt][nt] = __builtin_amdgcn_mfma_f32_16x16x32_bf16(
                    af[mt], bv[nt], acc[mt][nt], 0, 0, 0);
        __syncthreads();
    }

    const int wm = (wave >> 1) * 64, wn = (wave & 1) * 64;
    const int row0 = tm * 128 + wm + q * 4;
    const int col0 = tn * 128 + wn + r;
    if (CF32) {
        float* C = (float*)Cv;
        #pragma unroll
        for (int mt = 0; mt < 4; ++mt)
            #pragma unroll
            for (int i = 0; i < 4; ++i) {
                long rb = (long)(row0 + mt * 16 + i) * ldc + col0;
                #pragma unroll
                for (int nt = 0; nt < 4; ++nt)
                    C[rb + nt * 16] = acc[mt][nt][i];
            }
    } else {
        u16* C = (u16*)Cv;
        #pragma unroll
        for (int mt = 0; mt < 4; ++mt)
            #pragma unroll
            for (int i = 0; i < 4; ++i) {
                long rb = (long)(row0 + mt * 16 + i) * ldc + col0;
                #pragma unroll
                for (int nt = 0; nt < 4; ++nt)
                    C[rb + nt * 16] = f2bf(acc[mt][nt][i]);
            }
    }
}

// ---------------------------------------------------------------------------
// Flash attention v3: S^T form + split-k partials.
// Block = 256 thr (4 waves), q-tile 128 (wave w: q-cols w*32..+31 as two
// 16-col n-blocks), kv-tile 128, chunk = 4 kv-tiles. Grid (40, 16 heads):
// bx enumerates (j strip, c chunk) heavy-first (j=15 down).
// Maxless exp2 softmax -> partials are additive: block writes fp32 O + l
// into slot (h*40+bx); attn_reduce sums <=4 slots and normalizes.
// ---------------------------------------------------------------------------
__device__ __forceinline__ void kv_tile_step(
    const u16* __restrict__ Kl, const u16* __restrict__ Vl,
    const bf16x8 (&Qf)[2][6], f32x4 (&Oacc)[8][2], float (&lsum)[2],
    int lane, int quad, int r, int kglob0, int qg0, int qg1, bool maskT)
{
    f32x4 Sacc[8][2];
    #pragma unroll
    for (int mtk = 0; mtk < 8; ++mtk) {
        Sacc[mtk][0] = (f32x4){0.f, 0.f, 0.f, 0.f};
        Sacc[mtk][1] = (f32x4){0.f, 0.f, 0.f, 0.f};
    }
    #pragma unroll
    for (int kc = 0; kc < 6; ++kc)
        #pragma unroll
        for (int mtk = 0; mtk < 8; ++mtk) {
            bf16x8 Ak = *(const bf16x8*)&Kl[(mtk * 6 + kc) * 512 + lane * 8];
            Sacc[mtk][0] = __builtin_amdgcn_mfma_f32_16x16x32_bf16(
                Ak, Qf[0][kc], Sacc[mtk][0], 0, 0, 0);
            Sacc[mtk][1] = __builtin_amdgcn_mfma_f32_16x16x32_bf16(
                Ak, Qf[1][kc], Sacc[mtk][1], 0, 0, 0);
        }
    #pragma unroll
    for (int kb = 0; kb < 8; ++kb) {
        s16x4 Pf[2];
        const int kb0 = kglob0 + kb * 16 + quad * 4;
        #pragma unroll
        for (int n = 0; n < 2; ++n) {
            const int qg = n ? qg1 : qg0;
            #pragma unroll
            for (int i = 0; i < 4; ++i) {
                float p = exp2f(Sacc[kb][n][i]);
                if (maskT && (kb0 + i > qg)) p = 0.f;
                lsum[n] += p;
                Pf[n][i] = (short)f2bf(p);
            }
        }
        #pragma unroll
        for (int mtd = 0; mtd < 8; ++mtd) {
            s16x4 Av = *(const s16x4*)&Vl[(mtd * 4 + (kb >> 1)) * 512
                         + ((kb & 1) * 2 + (quad >> 1)) * 128 + r * 8 + (quad & 1) * 4];
            Oacc[mtd][0] = mfma16(Av, Pf[0], Oacc[mtd][0]);
            Oacc[mtd][1] = mfma16(Av, Pf[1], Oacc[mtd][1]);
        }
    }
}

__global__ __launch_bounds__(256, 2)
void flash_attn(const u16* __restrict__ query, const u16* __restrict__ kvb,
                const u16* __restrict__ kpe, const u16* __restrict__ vt,
                float* __restrict__ part, float* __restrict__ lpart)
{
    const int tid = threadIdx.x;
    const int w = tid >> 6, lane = tid & 63;
    const int quad = lane >> 4, r = lane & 15;
    const int bx = blockIdx.x, h = blockIdx.y;

    int j = 0, c = 0;
    {
        int acc = 0;
        for (int jj = 15; jj >= 0; --jj) {
            int nc = (jj + 4) >> 2;
            if (bx < acc + nc) { j = jj; c = bx - acc; break; }
            acc += nc;
        }
    }
    const int q0 = j * 128;
    const int ntk = j + 1;
    const int tkE = (c * 4 + 4 < ntk) ? c * 4 + 4 : ntk;

    __shared__ __align__(16) u16 Kl[24576];   // 48KB: 48 chunks (16k x 32d)
    __shared__ __align__(16) u16 Vl[16384];   // 32KB: 32 chunks (16d x 32s)

    const int qg0 = q0 + w * 32 + r;
    const int qg1 = qg0 + 16;

    bf16x8 Qf[2][6];
    #pragma unroll
    for (int n = 0; n < 2; ++n)
        #pragma unroll
        for (int kc = 0; kc < 6; ++kc)
            Qf[n][kc] = *(const bf16x8*)(query
                + ((size_t)h * S_LEN + q0 + w * 32 + n * 16 + r) * QHEAD
                + kc * 32 + quad * 8);

    f32x4 Oacc[8][2];
    #pragma unroll
    for (int mtd = 0; mtd < 8; ++mtd) {
        Oacc[mtd][0] = (f32x4){0.f, 0.f, 0.f, 0.f};
        Oacc[mtd][1] = (f32x4){0.f, 0.f, 0.f, 0.f};
    }
    float lsum[2] = {0.f, 0.f};

    for (int tk = c * 4; tk < tkE; ++tk) {
        // staging: 80 chunks total (48 K + 32 V); wave w does [w*20, w*20+20)
        #pragma unroll
        for (int cc = 0; cc < 20; ++cc) {
            int g = w * 20 + cc;
            if (g < 48) {
                int mtk = g / 6, kc = g % 6;
                int row = tk * 128 + mtk * 16 + r;
                const u16* src = (kc < 4)
                    ? kvb + (size_t)row * 4096 + h * 256 + kc * 32 + quad * 8
                    : kpe + (size_t)row * 64 + (kc - 4) * 32 + quad * 8;
                gl_lds16(src, &Kl[g * 512]);
            } else {
                int cv = g - 48, mtd = cv >> 2, sc = cv & 3;
                const u16* src = vt + ((size_t)h * 128 + mtd * 16 + r) * 2048
                                 + tk * 128 + sc * 32 + quad * 8;
                gl_lds16(src, &Vl[cv * 512]);
            }
        }
        __syncthreads();
        kv_tile_step(Kl, Vl, Qf, Oacc, lsum, lane, quad, r, tk * 128, qg0, qg1, tk == j);
        __syncthreads();
    }

    // epilogue: write fp32 partials to slot (h*40+bx)
    const size_t slot = (size_t)h * 40 + bx;
    #pragma unroll
    for (int n = 0; n < 2; ++n) {
        float l = lsum[n];
        l += __shfl_xor(l, 16, 64);
        l += __shfl_xor(l, 32, 64);
        const int qi = w * 32 + n * 16 + r;
        float* dst = part + (slot * 128 + qi) * 128;
        #pragma unroll
        for (int mtd = 0; mtd < 8; ++mtd)
            *(f32x4*)(dst + mtd * 16 + quad * 4) = Oacc[mtd][n];
        if (quad == 0) lpart[slot * 128 + qi] = l;
    }
}

// sum <=4 chunk partials, normalize, write ao bf16 [S][H*128]
__global__ __launch_bounds__(256)
void attn_reduce(const float* __restrict__ part, const float* __restrict__ lpart,
                 u16* __restrict__ ao)
{
    int idx = blockIdx.x * 256 + threadIdx.x;  // 16 h x 2048 q x 32 d4 = 2^20
    int d4 = idx & 31;
    int q  = (idx >> 5) & 2047;
    int h  = idx >> 16;
    int j = q >> 7, qi = q & 127;
    int base = 0;
    for (int jj = 15; jj > j; --jj) base += (jj + 4) >> 2;
    int nc = (j + 4) >> 2;
    f32x4 o = {0.f, 0.f, 0.f, 0.f};
    float l = 0.f;
    for (int c = 0; c < nc; ++c) {
        size_t slot = (size_t)h * 40 + base + c;
        o += *(const f32x4*)(part + (slot * 128 + qi) * 128 + d4 * 4);
        l += lpart[slot * 128 + qi];
    }
    float inv = 1.0f / l;
    ushort4 ov;
    ov.x = f2bf(o[0] * inv); ov.y = f2bf(o[1] * inv);
    ov.z = f2bf(o[2] * inv); ov.w = f2bf(o[3] * inv);
    *(ushort4*)(ao + (size_t)q * 2048 + h * 128 + d4 * 4) = ov;
}

// ---------------------------------------------------------------------------
__global__ __launch_bounds__(256)
void cvt_f32_bf16(const float4* __restrict__ in, ushort4* __restrict__ out, int n4)
{
    int i = blockIdx.x * 256 + threadIdx.x;
    if (i < n4) {
        float4 v = in[i];
        ushort4 o;
        o.x = f2bf(v.x); o.y = f2bf(v.y); o.z = f2bf(v.z); o.w = f2bf(v.w);
        out[i] = o;
    }
}

// all 5 weight transposes in one dispatch. fp32 [K][N] -> bf16 [Npad][K].
struct WT5 {
    const float* src[5];
    u16* dst[5];
    int K[5], Np[5], N[5], start[6];
};
__global__ __launch_bounds__(256)
void wtrans_multi(WT5 t)
{
    __shared__ float tile[32][33];
    int bid = blockIdx.x;
    int seg = 0;
    #pragma unroll
    for (int s = 0; s < 5; ++s)
        if (bid >= t.start[s]) seg = s;
    int local = bid - t.start[seg];
    int ntn = t.Np[seg] >> 5;
    int kt = local / ntn, nt = local - kt * ntn;
    const float* in = t.src[seg];
    u16* out = t.dst[seg];
    int K = t.K[seg], N = t.N[seg];
    int k0 = kt * 32, n0 = nt * 32;
    int tx = threadIdx.x, ty = threadIdx.y;
    #pragma unroll
    for (int jj = 0; jj < 32; jj += 8) {
        int n = n0 + tx;
        tile[ty + jj][tx] = (n < N) ? in[(long)(k0 + ty + jj) * N + n] : 0.0f;
    }
    __syncthreads();
    #pragma unroll
    for (int jj = 0; jj < 32; jj += 8)
        out[(long)(n0 + ty + jj) * K + k0 + tx] = f2bf(tile[tx][ty + jj]);
}

// fused: RMS-norm q_a (cols 0..1535, in place) + RMS-norm c (cols 1536..2047
// -> kvout fp32 / cnb bf16) + k_pe rope (cols 2048..2111 -> kvout / kpe).
__global__ __launch_bounds__(256)
void norm_fused(u16* __restrict__ qkv, const float* __restrict__ q_ln,
                const float* __restrict__ kv_ln, const int* __restrict__ pos_ids,
                const float* __restrict__ cosb, const float* __restrict__ sinb,
                float* __restrict__ kvout, u16* __restrict__ cnb,
                u16* __restrict__ kpe)
{
    const int s = blockIdx.x, tid = threadIdx.x;
    u16* row = qkv + (size_t)s * 2176;
    __shared__ float red1[4], red2[4];
    float s1 = 0.f, s2 = 0.f;
    for (int d = tid; d < 2048; d += 256) {
        float v = bf2f(row[d]); float v2 = v * v;
        if (d < 1536) s1 += v2; else s2 += v2;
    }
    #pragma unroll
    for (int o = 32; o; o >>= 1) { s1 += __shfl_xor(s1, o, 64); s2 += __shfl_xor(s2, o, 64); }
    if ((tid & 63) == 0) { red1[tid >> 6] = s1; red2[tid >> 6] = s2; }
    __syncthreads();
    s1 = red1[0] + red1[1] + red1[2] + red1[3];
    s2 = red2[0] + red2[1] + red2[2] + red2[3];
    const float sc1 = rsqrtf(s1 / 1536.f + EPS);
    const float sc2 = rsqrtf(s2 / 512.f + EPS);
    for (int d = tid; d < 1536; d += 256)
        row[d] = f2bf(bf2f(row[d]) * sc1 * q_ln[d]);
    for (int d = tid; d < 512; d += 256) {
        float v = bf2f(row[1536 + d]) * sc2 * kv_ln[d];
        kvout[(size_t)s * 576 + d] = v;
        cnb[(size_t)s * 512 + d] = f2bf(v);
    }
    if (tid < 32) {
        int p = pos_ids[s];
        float x0 = bf2f(row[2048 + 2 * tid]);
        float x1 = bf2f(row[2048 + 2 * tid + 1]);
        float c1 = cosb[p * 64 + tid], sn1 = sinb[p * 64 + tid];
        float c2 = cosb[p * 64 + 32 + tid], sn2 = sinb[p * 64 + 32 + tid];
        float lo = x0 * c1 - x1 * sn1;
        float hi = x1 * c2 + x0 * sn2;
        kvout[(size_t)s * 576 + 512 + tid] = lo;
        kvout[(size_t)s * 576 + 544 + tid] = hi;
        kpe[(size_t)s * 64 + tid] = f2bf(lo);
        kpe[(size_t)s * 64 + 32 + tid] = f2bf(hi);
    }
}

// q bf16 [S][3072] -> query bf16 [H][S][192], rope on last 64 dims,
// all values pre-scaled by SCALE*log2(e) for exp2-domain softmax.
__global__ __launch_bounds__(256)
void qrope_k(const u16* __restrict__ qb, const int* __restrict__ pos_ids,
             const float* __restrict__ cosb, const float* __restrict__ sinb,
             u16* __restrict__ query)
{
    const int s = blockIdx.x, tid = threadIdx.x;
    const u16* row = qb + (size_t)s * 3072;
    {
        int h = tid >> 4, c = tid & 15;
        const u16* src = &row[h * QHEAD + c * 8];
        u16* dst = &query[((size_t)(h * S_LEN + s)) * QHEAD + c * 8];
        ushort4 a = *(const ushort4*)src;
        ushort4 b = *(const ushort4*)(src + 4);
        ushort4 oa, ob;
        oa.x = f2bf(bf2f(a.x) * QSCALE_LOG2E); oa.y = f2bf(bf2f(a.y) * QSCALE_LOG2E);
        oa.z = f2bf(bf2f(a.z) * QSCALE_LOG2E); oa.w = f2bf(bf2f(a.w) * QSCALE_LOG2E);
        ob.x = f2bf(bf2f(b.x) * QSCALE_LOG2E); ob.y = f2bf(bf2f(b.y) * QSCALE_LOG2E);
        ob.z = f2bf(bf2f(b.z) * QSCALE_LOG2E); ob.w = f2bf(bf2f(b.w) * QSCALE_LOG2E);
        *(ushort4*)dst = oa;
        *(ushort4*)(dst + 4) = ob;
    }
    int p = pos_ids[s];
    for (int idx = tid; idx < 512; idx += 256) {
        int h = idx >> 5, i = idx & 31;
        float x0 = bf2f(row[h * QHEAD + 128 + 2 * i]);
        float x1 = bf2f(row[h * QHEAD + 128 + 2 * i + 1]);
        float c1 = cosb[p * 64 + i], sn1 = sinb[p * 64 + i];
        float c2 = cosb[p * 64 + 32 + i], sn2 = sinb[p * 64 + 32 + i];
        u16* qr = query + ((size_t)(h * S_LEN + s)) * QHEAD;
        qr[128 + i] = f2bf((x0 * c1 - x1 * sn1) * QSCALE_LOG2E);
        qr[160 + i] = f2bf((x1 * c2 + x0 * sn2) * QSCALE_LOG2E);
    }
}

// kv bf16 [S][4096] value part -> vt bf16 [H*128][S] (transposed)
__global__ __launch_bounds__(256)
void vtrans_k(const u16* __restrict__ kv, u16* __restrict__ vt)
{
    __shared__ u16 tile[32][33];
    int s0 = blockIdx.x * 32, d0 = blockIdx.y * 32, h = blockIdx.z;
    int tx = threadIdx.x, ty = threadIdx.y;
    #pragma unroll
    for (int jj = 0; jj < 32; jj += 8)
        tile[ty + jj][tx] = kv[(long)(s0 + ty + jj) * 4096 + h * 256 + 128 + d0 + tx];
    __syncthreads();
    #pragma unroll
    for (int jj = 0; jj < 32; jj += 8)
        vt[(long)(h * 128 + d0 + ty + jj) * S_LEN + s0 + tx] = tile[tx][ty + jj];
}

// ---------------------------------------------------------------------------
extern "C" void kernel_launch(void* const* d_in, const int* in_sizes, int n_in,
                              void* d_out, int out_size, void* d_ws, size_t ws_size,
                              hipStream_t stream)
{
    const float* x      = (const float*)d_in[0];
    const int*   posid  = (const int*)d_in[2];
    const float* cosb   = (const float*)d_in[3];
    const float* sinb   = (const float*)d_in[4];
    const float* q_a_w  = (const float*)d_in[5];
    const float* q_a_ln = (const float*)d_in[6];
    const float* q_b_w  = (const float*)d_in[7];
    const float* kv_a_w = (const float*)d_in[8];
    const float* kv_a_ln= (const float*)d_in[9];
    const float* kv_b_w = (const float*)d_in[10];
    const float* o_w    = (const float*)d_in[11];

    float* out    = (float*)d_out;
    float* kv_out = out + (size_t)2048 * 2048;

    char* ws = (char*)d_ws;
    size_t off = 0;
    auto alloc = [&](size_t bytes) { char* p = ws + off; off += (bytes + 255) & ~(size_t)255; return p; };
    // --- live-late buffers (alive during/after flash) ---
    u16* owt   = (u16*)alloc(2048ULL * 2048 * 2);
    u16* query = (u16*)alloc(16ULL * 2048 * 192 * 2);
    u16* kpe   = (u16*)alloc(2048ULL * 64 * 2);
    u16* kvbuf = (u16*)alloc(2048ULL * 4096 * 2);
    u16* vt    = (u16*)alloc(16ULL * 128 * 2048 * 2);
    u16* ao    = (u16*)alloc(2048ULL * 2048 * 2);
    // --- dead-early region (all dead before flash); part/lpart alias it ---
    size_t deadBase = off;
    u16* xb    = (u16*)alloc(2048ULL * 2048 * 2);
    u16* W1    = (u16*)alloc(2176ULL * 2048 * 2);   // [q_a^T ; kv_a^T(pad 640)]
    u16* qbwt  = (u16*)alloc(3072ULL * 1536 * 2);
    u16* kvbwt = (u16*)alloc(4096ULL * 512 * 2);
    u16* qkv_a = (u16*)alloc(2048ULL * 2176 * 2);   // [q_a(1536) | ckv(640)]
    u16* qbuf  = (u16*)alloc(2048ULL * 3072 * 2);
    u16* cnb   = (u16*)alloc(2048ULL * 512 * 2);
    float* part  = (float*)(ws + deadBase);          // 16*40*128*128 f32 = 41.9MB
    float* lpart = part + 16ULL * 40 * 128 * 128;    // + 0.33MB (fits in 54.5MB)
    (void)ws_size; (void)in_sizes; (void)n_in; (void)out_size;

    dim3 blk(256);
    dim3 tblk(32, 8);

    // 0) input convert + all weight transposes (one dispatch)
    cvt_f32_bf16<<<dim3(4096), blk, 0, stream>>>((const float4*)x, (ushort4*)xb, 2048 * 2048 / 4);
    WT5 t;
    t.src[0] = q_a_w;  t.dst[0] = W1;                  t.K[0] = 2048; t.Np[0] = 1536; t.N[0] = 1536;
    t.src[1] = kv_a_w; t.dst[1] = W1 + 1536ULL * 2048; t.K[1] = 2048; t.Np[1] = 640;  t.N[1] = 576;
    t.src[2] = q_b_w;  t.dst[2] = qbwt;                t.K[2] = 1536; t.Np[2] = 3072; t.N[2] = 3072;
    t.src[3] = kv_b_w; t.dst[3] = kvbwt;               t.K[3] = 512;  t.Np[3] = 4096; t.N[3] = 4096;
    t.src[4] = o_w;    t.dst[4] = owt;                 t.K[4] = 2048; t.Np[4] = 2048; t.N[4] = 2048;
    t.start[0] = 0;
    t.start[1] = t.start[0] + (2048 / 32) * (1536 / 32);   // 3072
    t.start[2] = t.start[1] + (2048 / 32) * (640 / 32);    // +1280
    t.start[3] = t.start[2] + (1536 / 32) * (3072 / 32);   // +4608
    t.start[4] = t.start[3] + (512 / 32) * (4096 / 32);    // +2048
    t.start[5] = t.start[4] + (2048 / 32) * (2048 / 32);   // +4096 = 15104
    wtrans_multi<<<dim3(t.start[5]), tblk, 0, stream>>>(t);

    // 1) [q_a | ckv] = x @ [q_a_w | kv_a_w]; fused norms + k_pe rope
    gemm_bt<0><<<dim3(17, 16), blk, 0, stream>>>(xb, W1, qkv_a, 2048, 2048, 2048, 2176);
    norm_fused<<<dim3(2048), blk, 0, stream>>>(qkv_a, q_a_ln, kv_a_ln, posid, cosb, sinb,
                                               kv_out, cnb, kpe);

    // 2) q = q_a_norm @ q_b_w ; rope + relayout (+ exp2-domain pre-scale)
    gemm_bt<0><<<dim3(24, 16), blk, 0, stream>>>(qkv_a, qbwt, qbuf, 1536, 2176, 1536, 3072);
    qrope_k<<<dim3(2048), blk, 0, stream>>>(qbuf, posid, cosb, sinb, query);

    // 3) kv = c_norm @ kv_b_w ; transpose value
    gemm_bt<0><<<dim3(32, 16), blk, 0, stream>>>(cnb, kvbwt, kvbuf, 512, 512, 512, 4096);
    vtrans_k<<<dim3(64, 4, 16), tblk, 0, stream>>>(kvbuf, vt);

    // 4) flash attention split-k -> partials -> reduce to ao
    flash_attn<<<dim3(40, 16), blk, 0, stream>>>(query, kvbuf, kpe, vt, part, lpart);
    attn_reduce<<<dim3(4096), blk, 0, stream>>>(part, lpart, ao);

    // 5) out = ao @ o_w (fp32)
    gemm_bt<1><<<dim3(16, 16), blk, 0, stream>>>(ao, owt, out, 2048, 2048, 2048, 2048);
}